// Round 6
// baseline (855.722 us; speedup 1.0000x reference)
//
#include <hip/hip_runtime.h>

#define E 256
#define OUTD 128
#define KSTEPS 128

typedef short bf16x8 __attribute__((ext_vector_type(8)));
typedef float f32x4 __attribute__((ext_vector_type(4)));
typedef unsigned short ushort_t;
typedef unsigned int uint_t;

__device__ __forceinline__ ushort_t f2bf(float f){
  union { float f; uint_t u; } v; v.f = f;
  uint_t r = (v.u + 0x7FFFu + ((v.u >> 16) & 1u)) >> 16;
  return (ushort_t)r;
}
__device__ __forceinline__ float sigmoid_(float x){ return 1.f/(1.f + __expf(-x)); }
__device__ __forceinline__ float tanh_(float x){ return 2.f/(1.f + __expf(-2.f*x)) - 1.f; }
// Pin a fragment into the ACCUMULATION register file (AGPRs). gfx950 MFMA
// reads A/B operands directly from AGPRs, so these cost no per-use copies,
// and they don't count against the 128-arch-VGPR budget that R3-R5 kept
// overflowing into scratch.
__device__ __forceinline__ void pin_a(bf16x8& x){ asm volatile("" : "+a"(x)); }
// Per-step barrier: drain LDS ops only; global (weight) prefetches stay in
// flight across the barrier (counted-vmcnt pattern).
__device__ __forceinline__ void step_barrier(){
  asm volatile("s_waitcnt lgkmcnt(0)" ::: "memory");
  __builtin_amdgcn_s_barrier();
}

// ---------------------------------------------------------------------------
// Prep: build bf16 weight-fragment arrays in ws (unchanged).
//   Wc (steps>=1): [r+z combined | W_ih_n | W_hh_n]  -> G cols [0,1024)
//   W0 (step 0):   [W_hh_r | W_hh_z | 0 | W_hh_n]
//   Wo:            W_out fragments
// frag(t,kk,l,j) = W[k][c], c = t*16 + (l&15), k = kk*32 + (l>>4)*8 + j
// ---------------------------------------------------------------------------
__global__ void prep_weights(const float* __restrict__ W_ih,
                             const float* __restrict__ W_hh,
                             const float* __restrict__ W_out,
                             ushort_t* __restrict__ ws)
{
  int fragIdx = blockIdx.x * blockDim.x + threadIdx.x;  // 0..69631
  if (fragIdx >= 69632) return;
  int arr, f;
  if (fragIdx < 32768)      { arr = 0; f = fragIdx; }
  else if (fragIdx < 65536) { arr = 1; f = fragIdx - 32768; }
  else                      { arr = 2; f = fragIdx - 65536; }
  int l  = f & 63;
  int tk = f >> 6;
  int kk = tk & 7;
  int t  = tk >> 3;
  int c  = t*16 + (l & 15);
  int kbase = kk*32 + (l >> 4)*8;
  bf16x8 v8;
#pragma unroll
  for (int j = 0; j < 8; j++){
    int k = kbase + j;
    float v;
    if (arr == 0){
      v = (c < 512) ? (W_ih[c*E + k] + W_hh[c*E + k])
        : (c < 768) ? W_ih[c*E + k]
                    : W_hh[(c-256)*E + k];
    } else if (arr == 1){
      v = (c < 512) ? W_hh[c*E + k]
        : (c < 768) ? 0.f
                    : W_hh[(c-256)*E + k];
    } else {
      v = W_out[c*E + k];
    }
    v8[j] = (short)f2bf(v);
  }
  *reinterpret_cast<bf16x8*>(ws + (size_t)fragIdx * 8) = v8;
}

// ---------------------------------------------------------------------------
// Main persistent kernel: 128 blocks x 512 threads (8 waves), 1 block/CU.
//   AGPR (pinned, "a" constraint): combined r,z tiles = 128 regs/wave
//   VGPR: acc/prefetch/temporaries ~116 regs -> fits the 128 arch cap
//   LDS:  W_ih_n tiles (128 KB) + h double-buffer (2 x 8 KB)
//   L2:   W_hh_n + W_out streamed per step, depth-2 rotating prefetch
//         spanning the per-step raw barrier
// ---------------------------------------------------------------------------
__global__ void __launch_bounds__(512)
__attribute__((amdgpu_waves_per_eu(2, 2))) gru_main(
    const float* __restrict__ c_in,  const float* __restrict__ b_ih,
    const float* __restrict__ b_hh,  const float* __restrict__ b_out,
    const ushort_t* __restrict__ WcB, const ushort_t* __restrict__ W0B,
    const ushort_t* __restrict__ WoB, float* __restrict__ out)
{
  __shared__ __align__(16) ushort_t lw[65536];      // W_ih_n, 128 KB
  __shared__ __align__(16) ushort_t hbf[2][4096];   // h dbuf, 2 x 8 KB

  const int tid = threadIdx.x;
  const int w   = tid >> 6;
  const int l   = tid & 63;
  const int l15 = l & 15;
  const int lg  = l >> 4;
  const int r0  = blockIdx.x << 4;

  float brz_r[2], brz_z[2], b_in_[2], b_hn_[2];
  float hreg[2][4];
#pragma unroll
  for (int ct = 0; ct < 2; ct++){
    int c = w*32 + ct*16 + l15;
    brz_r[ct] = b_ih[c]       + b_hh[c];
    brz_z[ct] = b_ih[256 + c] + b_hh[256 + c];
    b_in_[ct] = b_ih[512 + c];
    b_hn_[ct] = b_hh[512 + c];
#pragma unroll
    for (int i = 0; i < 4; i++){
      int m = lg*4 + i;
      hreg[ct][i] = c_in[(r0 + m)*E + c];
    }
  }
  const float bo = b_out[w*16 + l15];

  // ---- AGPR-resident (pinned): combined r,z tiles (128 AGPRs)
  bf16x8 wrz[4][8];   // [(g*2+ct)][kk], g=0:r g=1:z
#pragma unroll
  for (int g = 0; g < 2; g++)
#pragma unroll
    for (int ct = 0; ct < 2; ct++)
#pragma unroll
      for (int kk = 0; kk < 8; kk++){
        wrz[g*2+ct][kk] = *reinterpret_cast<const bf16x8*>(
            WcB + (((g*16 + w*2 + ct)*8 + kk)*64 + l)*8);
        pin_a(wrz[g*2+ct][kk]);
      }

  // ---- W_ih_n tiles (tg 32..47) -> LDS, linear 128 KB copy
  {
    const ushort_t* src = WcB + 32*4096;
#pragma unroll
    for (int i = 0; i < 16; i++){
      int idx = i*512 + tid;   // 16B units
      *reinterpret_cast<bf16x8*>(lw + idx*8) =
          *reinterpret_cast<const bf16x8*>(src + idx*8);
    }
  }

  // ---- initial h0 -> LDS buf 0 (bf16, swizzled)
  {
    char* hbW = reinterpret_cast<char*>(hbf[0]);
#pragma unroll
    for (int ct = 0; ct < 2; ct++)
#pragma unroll
      for (int i = 0; i < 4; i++){
        int m = lg*4 + i;
        int c = w*32 + ct*16 + l15;
        int cb = (c*2) ^ ((m & 7) << 4);
        *reinterpret_cast<ushort_t*>(hbW + m*512 + cb) = f2bf(hreg[ct][i]);
      }
  }
  __syncthreads();

  bf16x8 pf[2][3];   // depth-2 rotating prefetch: {bh0, bh1, wo}

  // ================= step 0 (peeled): x=0 -> in-part zero ==================
  {
    const char* hbR = reinterpret_cast<const char*>(hbf[0]);
    char*       hbW = reinterpret_cast<char*>(hbf[1]);
    f32x4 acc0[2], acc1[2], acc3[2];
#pragma unroll
    for (int ct = 0; ct < 2; ct++){
      acc0[ct] = (f32x4){0.f,0.f,0.f,0.f};
      acc1[ct] = (f32x4){0.f,0.f,0.f,0.f};
      acc3[ct] = (f32x4){0.f,0.f,0.f,0.f};
    }
#pragma unroll
    for (int kk = 0; kk < 8; kk++){
      int cb = (kk*64 + lg*16) ^ ((l15 & 7) << 4);
      bf16x8 a = *reinterpret_cast<const bf16x8*>(hbR + l15*512 + cb);
#pragma unroll
      for (int ct = 0; ct < 2; ct++){
        bf16x8 br = *reinterpret_cast<const bf16x8*>(W0B + (((0*16 + w*2 + ct)*8 + kk)*64 + l)*8);
        bf16x8 bz = *reinterpret_cast<const bf16x8*>(W0B + (((1*16 + w*2 + ct)*8 + kk)*64 + l)*8);
        bf16x8 bn = *reinterpret_cast<const bf16x8*>(W0B + (((3*16 + w*2 + ct)*8 + kk)*64 + l)*8);
        acc0[ct] = __builtin_amdgcn_mfma_f32_16x16x32_bf16(a, br, acc0[ct], 0, 0, 0);
        acc1[ct] = __builtin_amdgcn_mfma_f32_16x16x32_bf16(a, bz, acc1[ct], 0, 0, 0);
        acc3[ct] = __builtin_amdgcn_mfma_f32_16x16x32_bf16(a, bn, acc3[ct], 0, 0, 0);
      }
    }
#pragma unroll
    for (int ct = 0; ct < 2; ct++)
#pragma unroll
      for (int i = 0; i < 4; i++){
        float r = sigmoid_(acc0[ct][i] + brz_r[ct]);
        float z = sigmoid_(acc1[ct][i] + brz_z[ct]);
        float n = tanh_(b_in_[ct] + r*(acc3[ct][i] + b_hn_[ct]));
        hreg[ct][i] = (1.f - z)*n + z*hreg[ct][i];
      }
#pragma unroll
    for (int ct = 0; ct < 2; ct++)
#pragma unroll
      for (int i = 0; i < 4; i++){
        int m = lg*4 + i;
        int c = w*32 + ct*16 + l15;
        int cb = (c*2) ^ ((m & 7) << 4);
        *reinterpret_cast<ushort_t*>(hbW + m*512 + cb) = f2bf(hreg[ct][i]);
      }
    // prime prefetch window for step 1 (kk = 0, 1)
#pragma unroll
    for (int d = 0; d < 2; d++){
      pf[d][0] = *reinterpret_cast<const bf16x8*>(WcB + (((48 + w*2 + 0)*8 + d)*64 + l)*8);
      pf[d][1] = *reinterpret_cast<const bf16x8*>(WcB + (((48 + w*2 + 1)*8 + d)*64 + l)*8);
      pf[d][2] = *reinterpret_cast<const bf16x8*>(WoB + ((w*8 + d)*64 + l)*8);
    }
    step_barrier();
  }

  // ================= steps 1..127 ==========================================
#pragma unroll 1
  for (int k = 1; k < KSTEPS; k++){
    const char* hbR = reinterpret_cast<const char*>(hbf[k & 1]);
    char*       hbW = reinterpret_cast<char*>(hbf[(k + 1) & 1]);
    f32x4 acc[4][2];
#pragma unroll
    for (int g = 0; g < 4; g++)
#pragma unroll
      for (int ct = 0; ct < 2; ct++)
        acc[g][ct] = (f32x4){0.f, 0.f, 0.f, 0.f};
    f32x4 aco = {0.f, 0.f, 0.f, 0.f};

#pragma unroll
    for (int kk = 0; kk < 8; kk++){
      // consume current window slot
      bf16x8 ch0 = pf[kk & 1][0];
      bf16x8 ch1 = pf[kk & 1][1];
      bf16x8 cwo = pf[kk & 1][2];
      // refill slot with kk+2 (wraps to next step's kk=0,1 at kk=6,7 —
      // addresses are k-invariant; raw step_barrier keeps them in flight)
      {
        int nk = (kk + 2) & 7;
        pf[kk & 1][0] = *reinterpret_cast<const bf16x8*>(WcB + (((48 + w*2 + 0)*8 + nk)*64 + l)*8);
        pf[kk & 1][1] = *reinterpret_cast<const bf16x8*>(WcB + (((48 + w*2 + 1)*8 + nk)*64 + l)*8);
        pf[kk & 1][2] = *reinterpret_cast<const bf16x8*>(WoB + ((w*8 + nk)*64 + l)*8);
      }
      int cb = (kk*64 + lg*16) ^ ((l15 & 7) << 4);
      bf16x8 a   = *reinterpret_cast<const bf16x8*>(hbR + l15*512 + cb);
      bf16x8 bi0 = *reinterpret_cast<const bf16x8*>(lw + ((w*16 + 0*8 + kk)*64 + l)*8);
      bf16x8 bi1 = *reinterpret_cast<const bf16x8*>(lw + ((w*16 + 1*8 + kk)*64 + l)*8);
      acc[0][0] = __builtin_amdgcn_mfma_f32_16x16x32_bf16(a, wrz[0][kk], acc[0][0], 0, 0, 0);
      acc[0][1] = __builtin_amdgcn_mfma_f32_16x16x32_bf16(a, wrz[1][kk], acc[0][1], 0, 0, 0);
      acc[1][0] = __builtin_amdgcn_mfma_f32_16x16x32_bf16(a, wrz[2][kk], acc[1][0], 0, 0, 0);
      acc[1][1] = __builtin_amdgcn_mfma_f32_16x16x32_bf16(a, wrz[3][kk], acc[1][1], 0, 0, 0);
      acc[2][0] = __builtin_amdgcn_mfma_f32_16x16x32_bf16(a, bi0, acc[2][0], 0, 0, 0);
      acc[2][1] = __builtin_amdgcn_mfma_f32_16x16x32_bf16(a, bi1, acc[2][1], 0, 0, 0);
      acc[3][0] = __builtin_amdgcn_mfma_f32_16x16x32_bf16(a, ch0, acc[3][0], 0, 0, 0);
      acc[3][1] = __builtin_amdgcn_mfma_f32_16x16x32_bf16(a, ch1, acc[3][1], 0, 0, 0);
      aco = __builtin_amdgcn_mfma_f32_16x16x32_bf16(a, cwo, aco, 0, 0, 0);
    }

    // out_{k-1} = h_k @ Wout^T + b_out   (y_{k-1} == h_k)
#pragma unroll
    for (int i = 0; i < 4; i++){
      int m = lg*4 + i;
      out[((r0 + m)*KSTEPS + (k - 1))*OUTD + w*16 + l15] = aco[i] + bo;
    }

    // elementwise GRU update (in-register, D-layout match)
#pragma unroll
    for (int ct = 0; ct < 2; ct++){
#pragma unroll
      for (int i = 0; i < 4; i++){
        float r = sigmoid_(acc[0][ct][i] + brz_r[ct]);
        float z = sigmoid_(acc[1][ct][i] + brz_z[ct]);
        float n = tanh_(acc[2][ct][i] + b_in_[ct] + r*(acc[3][ct][i] + b_hn_[ct]));
        hreg[ct][i] = (1.f - z)*n + z*hreg[ct][i];
      }
    }

    // write h_{k+1} into the other buffer (no WAR: all reads of hbW's old
    // contents completed before the previous barrier)
#pragma unroll
    for (int ct = 0; ct < 2; ct++)
#pragma unroll
      for (int i = 0; i < 4; i++){
        int m = lg*4 + i;
        int c = w*32 + ct*16 + l15;
        int cb = (c*2) ^ ((m & 7) << 4);
        *reinterpret_cast<ushort_t*>(hbW + m*512 + cb) = f2bf(hreg[ct][i]);
      }
    step_barrier();   // LDS drained; global prefetches remain in flight
  }

  // epilogue: out_127 = h_128 @ Wout^T + b_out  (h_128 is in hbf[0])
  {
    const char* hbR = reinterpret_cast<const char*>(hbf[0]);
    f32x4 aco = {0.f, 0.f, 0.f, 0.f};
#pragma unroll
    for (int kk = 0; kk < 8; kk++){
      int cb = (kk*64 + lg*16) ^ ((l15 & 7) << 4);
      bf16x8 a  = *reinterpret_cast<const bf16x8*>(hbR + l15*512 + cb);
      bf16x8 wo0 = *reinterpret_cast<const bf16x8*>(WoB + ((w*8 + kk)*64 + l)*8);
      aco = __builtin_amdgcn_mfma_f32_16x16x32_bf16(a, wo0, aco, 0, 0, 0);
    }
#pragma unroll
    for (int i = 0; i < 4; i++){
      int m = lg*4 + i;
      out[((r0 + m)*KSTEPS + 127)*OUTD + w*16 + l15] = aco[i] + bo;
    }
  }
}

extern "C" void kernel_launch(void* const* d_in, const int* in_sizes, int n_in,
                              void* d_out, int out_size, void* d_ws, size_t ws_size,
                              hipStream_t stream)
{
  const float* c     = (const float*)d_in[0];
  const float* W_ih  = (const float*)d_in[1];
  const float* W_hh  = (const float*)d_in[2];
  const float* b_ih  = (const float*)d_in[3];
  const float* b_hh  = (const float*)d_in[4];
  const float* W_out = (const float*)d_in[5];
  const float* b_out = (const float*)d_in[6];

  ushort_t* ws  = (ushort_t*)d_ws;
  ushort_t* WcB = ws;              // 262144 bf16
  ushort_t* W0B = ws + 262144;     // 262144 bf16
  ushort_t* WoB = ws + 524288;     //  32768 bf16

  hipLaunchKernelGGL(prep_weights, dim3(272), dim3(256), 0, stream,
                     W_ih, W_hh, W_out, ws);
  hipLaunchKernelGGL(gru_main, dim3(128), dim3(512), 0, stream,
                     c, b_ih, b_hh, b_out, WcB, W0B, WoB, (float*)d_out);
}

// Round 8
// 729.627 us; speedup vs baseline: 1.1728x; 1.1728x over previous
//
#include <hip/hip_runtime.h>

#define E 256
#define OUTD 128
#define KSTEPS 128

typedef short bf16x8 __attribute__((ext_vector_type(8)));
typedef float f32x4 __attribute__((ext_vector_type(4)));
typedef unsigned short ushort_t;
typedef unsigned int uint_t;

__device__ __forceinline__ ushort_t f2bf(float f){
  union { float f; uint_t u; } v; v.f = f;
  uint_t r = (v.u + 0x7FFFu + ((v.u >> 16) & 1u)) >> 16;
  return (ushort_t)r;
}
__device__ __forceinline__ float sigmoid_(float x){ return 1.f/(1.f + __expf(-x)); }
__device__ __forceinline__ float tanh_(float x){ return 2.f/(1.f + __expf(-2.f*x)) - 1.f; }
// Force a loaded weight fragment into the ACCUMULATION file and make it
// non-rematerializable (volatile). All its uses are "a"-constrained MFMAs,
// so the whole live range stays AGPR: 128 regs of weights resident without
// touching the 128-arch-VGPR half.
__device__ __forceinline__ void pin_a(bf16x8& x){ asm volatile("" : "+a"(x)); }
// Inline-asm MFMA: B operand in AGPR / VGPR. D forced to VGPR so the
// accumulators never compete with the pinned weights for AGPRs.
// HAZARD DISCIPLINE: the compiler's hazard recognizer does not see MFMAs
// inside inline asm, so required wait states around these are inserted
// manually (see fences below).
__device__ __forceinline__ void mfma_va(f32x4& d, bf16x8 a, bf16x8 b){
  asm("v_mfma_f32_16x16x32_bf16 %0, %1, %2, %0" : "+v"(d) : "v"(a), "a"(b));
}
__device__ __forceinline__ void mfma_vv(f32x4& d, bf16x8 a, bf16x8 b){
  asm("v_mfma_f32_16x16x32_bf16 %0, %1, %2, %0" : "+v"(d) : "v"(a), "v"(b));
}
// Per-step barrier: drain LDS ops only; global prefetches stay in flight.
__device__ __forceinline__ void step_barrier(){
  asm volatile("s_waitcnt lgkmcnt(0)" ::: "memory");
  __builtin_amdgcn_s_barrier();
}

// ---------------------------------------------------------------------------
// Prep: build bf16 weight-fragment arrays in ws (unchanged).
//   Wc (steps>=1): [r+z combined | W_ih_n | W_hh_n]  -> G cols [0,1024)
//   W0 (step 0):   [W_hh_r | W_hh_z | 0 | W_hh_n]
//   Wo:            W_out fragments
// frag(t,kk,l,j) = W[k][c], c = t*16 + (l&15), k = kk*32 + (l>>4)*8 + j
// ---------------------------------------------------------------------------
__global__ void prep_weights(const float* __restrict__ W_ih,
                             const float* __restrict__ W_hh,
                             const float* __restrict__ W_out,
                             ushort_t* __restrict__ ws)
{
  int fragIdx = blockIdx.x * blockDim.x + threadIdx.x;  // 0..69631
  if (fragIdx >= 69632) return;
  int arr, f;
  if (fragIdx < 32768)      { arr = 0; f = fragIdx; }
  else if (fragIdx < 65536) { arr = 1; f = fragIdx - 32768; }
  else                      { arr = 2; f = fragIdx - 65536; }
  int l  = f & 63;
  int tk = f >> 6;
  int kk = tk & 7;
  int t  = tk >> 3;
  int c  = t*16 + (l & 15);
  int kbase = kk*32 + (l >> 4)*8;
  bf16x8 v8;
#pragma unroll
  for (int j = 0; j < 8; j++){
    int k = kbase + j;
    float v;
    if (arr == 0){
      v = (c < 512) ? (W_ih[c*E + k] + W_hh[c*E + k])
        : (c < 768) ? W_ih[c*E + k]
                    : W_hh[(c-256)*E + k];
    } else if (arr == 1){
      v = (c < 512) ? W_hh[c*E + k]
        : (c < 768) ? 0.f
                    : W_hh[(c-256)*E + k];
    } else {
      v = W_out[c*E + k];
    }
    v8[j] = (short)f2bf(v);
  }
  *reinterpret_cast<bf16x8*>(ws + (size_t)fragIdx * 8) = v8;
}

// ---------------------------------------------------------------------------
// Main persistent kernel: 128 blocks x 512 threads (8 waves), 1 block/CU.
//   AGPR (pinned + "a"-constrained uses): combined r,z tiles = 128 regs/wave
//   VGPR: acc(36, forced "v") + pf(24) + temps ~= 110 -> fits 128 arch half
//   LDS:  W_ih_n tiles (128 KB) + h double-buffer (2 x 8 KB)
//   L2:   W_hh_n + W_out streamed per step, depth-2 rotating prefetch
// ---------------------------------------------------------------------------
__global__ void __launch_bounds__(512)
__attribute__((amdgpu_waves_per_eu(2, 2))) gru_main(
    const float* __restrict__ c_in,  const float* __restrict__ b_ih,
    const float* __restrict__ b_hh,  const float* __restrict__ b_out,
    const ushort_t* __restrict__ WcB, const ushort_t* __restrict__ W0B,
    const ushort_t* __restrict__ WoB, float* __restrict__ out)
{
  __shared__ __align__(16) ushort_t lw[65536];      // W_ih_n, 128 KB
  __shared__ __align__(16) ushort_t hbf[2][4096];   // h dbuf, 2 x 8 KB

  const int tid = threadIdx.x;
  const int w   = tid >> 6;
  const int l   = tid & 63;
  const int l15 = l & 15;
  const int lg  = l >> 4;
  const int r0  = blockIdx.x << 4;

  float brz_r[2], brz_z[2], b_in_[2], b_hn_[2];
  float hreg[2][4];
#pragma unroll
  for (int ct = 0; ct < 2; ct++){
    int c = w*32 + ct*16 + l15;
    brz_r[ct] = b_ih[c]       + b_hh[c];
    brz_z[ct] = b_ih[256 + c] + b_hh[256 + c];
    b_in_[ct] = b_ih[512 + c];
    b_hn_[ct] = b_hh[512 + c];
#pragma unroll
    for (int i = 0; i < 4; i++){
      int m = lg*4 + i;
      hreg[ct][i] = c_in[(r0 + m)*E + c];
    }
  }
  const float bo = b_out[w*16 + l15];

  // ---- AGPR-resident weights: combined r,z tiles (128 AGPRs, pinned)
  bf16x8 wrz[4][8];   // [(g*2+ct)][kk], g=0:r g=1:z
#pragma unroll
  for (int g = 0; g < 2; g++)
#pragma unroll
    for (int ct = 0; ct < 2; ct++)
#pragma unroll
      for (int kk = 0; kk < 8; kk++){
        wrz[g*2+ct][kk] = *reinterpret_cast<const bf16x8*>(
            WcB + (((g*16 + w*2 + ct)*8 + kk)*64 + l)*8);
        pin_a(wrz[g*2+ct][kk]);
      }

  // ---- W_ih_n tiles (tg 32..47) -> LDS, linear 128 KB copy
  {
    const ushort_t* src = WcB + 32*4096;
#pragma unroll
    for (int i = 0; i < 16; i++){
      int idx = i*512 + tid;   // 16B units
      *reinterpret_cast<bf16x8*>(lw + idx*8) =
          *reinterpret_cast<const bf16x8*>(src + idx*8);
    }
  }

  // ---- initial h0 -> LDS buf 0 (bf16, swizzled)
  {
    char* hbW = reinterpret_cast<char*>(hbf[0]);
#pragma unroll
    for (int ct = 0; ct < 2; ct++)
#pragma unroll
      for (int i = 0; i < 4; i++){
        int m = lg*4 + i;
        int c = w*32 + ct*16 + l15;
        int cb = (c*2) ^ ((m & 7) << 4);
        *reinterpret_cast<ushort_t*>(hbW + m*512 + cb) = f2bf(hreg[ct][i]);
      }
  }
  __syncthreads();

  bf16x8 pf[2][3];   // depth-2 rotating prefetch: {bh0, bh1, wo}

  // ================= step 0 (peeled): x=0 -> in-part zero ==================
  // Builtin MFMAs here (compiler-managed hazards); streams from W0B once.
  {
    const char* hbR = reinterpret_cast<const char*>(hbf[0]);
    char*       hbW = reinterpret_cast<char*>(hbf[1]);
    f32x4 acc0[2], acc1[2], acc3[2];
#pragma unroll
    for (int ct = 0; ct < 2; ct++){
      acc0[ct] = (f32x4){0.f,0.f,0.f,0.f};
      acc1[ct] = (f32x4){0.f,0.f,0.f,0.f};
      acc3[ct] = (f32x4){0.f,0.f,0.f,0.f};
    }
#pragma unroll
    for (int kk = 0; kk < 8; kk++){
      int cb = (kk*64 + lg*16) ^ ((l15 & 7) << 4);
      bf16x8 a = *reinterpret_cast<const bf16x8*>(hbR + l15*512 + cb);
#pragma unroll
      for (int ct = 0; ct < 2; ct++){
        bf16x8 br = *reinterpret_cast<const bf16x8*>(W0B + (((0*16 + w*2 + ct)*8 + kk)*64 + l)*8);
        bf16x8 bz = *reinterpret_cast<const bf16x8*>(W0B + (((1*16 + w*2 + ct)*8 + kk)*64 + l)*8);
        bf16x8 bn = *reinterpret_cast<const bf16x8*>(W0B + (((3*16 + w*2 + ct)*8 + kk)*64 + l)*8);
        acc0[ct] = __builtin_amdgcn_mfma_f32_16x16x32_bf16(a, br, acc0[ct], 0, 0, 0);
        acc1[ct] = __builtin_amdgcn_mfma_f32_16x16x32_bf16(a, bz, acc1[ct], 0, 0, 0);
        acc3[ct] = __builtin_amdgcn_mfma_f32_16x16x32_bf16(a, bn, acc3[ct], 0, 0, 0);
      }
    }
#pragma unroll
    for (int ct = 0; ct < 2; ct++)
#pragma unroll
      for (int i = 0; i < 4; i++){
        float r = sigmoid_(acc0[ct][i] + brz_r[ct]);
        float z = sigmoid_(acc1[ct][i] + brz_z[ct]);
        float n = tanh_(b_in_[ct] + r*(acc3[ct][i] + b_hn_[ct]));
        hreg[ct][i] = (1.f - z)*n + z*hreg[ct][i];
      }
#pragma unroll
    for (int ct = 0; ct < 2; ct++)
#pragma unroll
      for (int i = 0; i < 4; i++){
        int m = lg*4 + i;
        int c = w*32 + ct*16 + l15;
        int cb = (c*2) ^ ((m & 7) << 4);
        *reinterpret_cast<ushort_t*>(hbW + m*512 + cb) = f2bf(hreg[ct][i]);
      }
    // prime prefetch window for step 1 (kk = 0, 1)
#pragma unroll
    for (int d = 0; d < 2; d++){
      pf[d][0] = *reinterpret_cast<const bf16x8*>(WcB + (((48 + w*2 + 0)*8 + d)*64 + l)*8);
      pf[d][1] = *reinterpret_cast<const bf16x8*>(WcB + (((48 + w*2 + 1)*8 + d)*64 + l)*8);
      pf[d][2] = *reinterpret_cast<const bf16x8*>(WoB + ((w*8 + d)*64 + l)*8);
    }
    step_barrier();
  }

  // ================= steps 1..127 ==========================================
#pragma unroll 1
  for (int k = 1; k < KSTEPS; k++){
    const char* hbR = reinterpret_cast<const char*>(hbf[k & 1]);
    char*       hbW = reinterpret_cast<char*>(hbf[(k + 1) & 1]);
    f32x4 acc[4][2];
#pragma unroll
    for (int g = 0; g < 4; g++)
#pragma unroll
      for (int ct = 0; ct < 2; ct++)
        acc[g][ct] = (f32x4){0.f, 0.f, 0.f, 0.f};
    f32x4 aco = {0.f, 0.f, 0.f, 0.f};

    // HAZARD pre-fence: VALU zero-init -> asm-MFMA srcC read needs 2 waits.
    asm volatile("s_nop 1"
      : "+v"(acc[0][0]), "+v"(acc[0][1]), "+v"(acc[1][0]), "+v"(acc[1][1]),
        "+v"(acc[2][0]), "+v"(acc[2][1]), "+v"(acc[3][0]), "+v"(acc[3][1]),
        "+v"(aco));

#pragma unroll
    for (int kk = 0; kk < 8; kk++){
      // consume current window slot
      bf16x8 ch0 = pf[kk & 1][0];
      bf16x8 ch1 = pf[kk & 1][1];
      bf16x8 cwo = pf[kk & 1][2];
      // refill slot with kk+2 (wraps to next step's kk=0,1 at kk=6,7 —
      // addresses are k-invariant; step_barrier keeps them in flight)
      {
        int nk = (kk + 2) & 7;
        pf[kk & 1][0] = *reinterpret_cast<const bf16x8*>(WcB + (((48 + w*2 + 0)*8 + nk)*64 + l)*8);
        pf[kk & 1][1] = *reinterpret_cast<const bf16x8*>(WcB + (((48 + w*2 + 1)*8 + nk)*64 + l)*8);
        pf[kk & 1][2] = *reinterpret_cast<const bf16x8*>(WoB + ((w*8 + nk)*64 + l)*8);
      }
      int cb = (kk*64 + lg*16) ^ ((l15 & 7) << 4);
      bf16x8 a   = *reinterpret_cast<const bf16x8*>(hbR + l15*512 + cb);
      bf16x8 bi0 = *reinterpret_cast<const bf16x8*>(lw + ((w*16 + 0*8 + kk)*64 + l)*8);
      bf16x8 bi1 = *reinterpret_cast<const bf16x8*>(lw + ((w*16 + 1*8 + kk)*64 + l)*8);
      // r,z gates: weights AGPR-resident
      mfma_va(acc[0][0], a, wrz[0][kk]);
      mfma_va(acc[0][1], a, wrz[1][kk]);
      mfma_va(acc[1][0], a, wrz[2][kk]);
      mfma_va(acc[1][1], a, wrz[3][kk]);
      // n-gate in-part from LDS, hn-part + Wout from streamed regs
      mfma_vv(acc[2][0], a, bi0);
      mfma_vv(acc[2][1], a, bi1);
      mfma_vv(acc[3][0], a, ch0);
      mfma_vv(acc[3][1], a, ch1);
      mfma_vv(aco,       a, cwo);
    }

    // HAZARD post-fence: asm-MFMA VGPR writes -> VALU reads need up to ~16
    // waits; route every accumulator through the fence so no read can be
    // scheduled above it.
    asm volatile("s_nop 7\n\ts_nop 7"
      : "+v"(acc[0][0]), "+v"(acc[0][1]), "+v"(acc[1][0]), "+v"(acc[1][1]),
        "+v"(acc[2][0]), "+v"(acc[2][1]), "+v"(acc[3][0]), "+v"(acc[3][1]),
        "+v"(aco));

    // out_{k-1} = h_k @ Wout^T + b_out   (y_{k-1} == h_k)
#pragma unroll
    for (int i = 0; i < 4; i++){
      int m = lg*4 + i;
      out[((r0 + m)*KSTEPS + (k - 1))*OUTD + w*16 + l15] = aco[i] + bo;
    }

    // elementwise GRU update (in-register, D-layout match)
#pragma unroll
    for (int ct = 0; ct < 2; ct++){
#pragma unroll
      for (int i = 0; i < 4; i++){
        float r = sigmoid_(acc[0][ct][i] + brz_r[ct]);
        float z = sigmoid_(acc[1][ct][i] + brz_z[ct]);
        float n = tanh_(acc[2][ct][i] + b_in_[ct] + r*(acc[3][ct][i] + b_hn_[ct]));
        hreg[ct][i] = (1.f - z)*n + z*hreg[ct][i];
      }
    }

    // write h_{k+1} into the other buffer (no WAR: all reads of hbW's old
    // contents completed before the previous barrier)
#pragma unroll
    for (int ct = 0; ct < 2; ct++)
#pragma unroll
      for (int i = 0; i < 4; i++){
        int m = lg*4 + i;
        int c = w*32 + ct*16 + l15;
        int cb = (c*2) ^ ((m & 7) << 4);
        *reinterpret_cast<ushort_t*>(hbW + m*512 + cb) = f2bf(hreg[ct][i]);
      }
    step_barrier();   // LDS drained; global prefetches remain in flight
  }

  // epilogue: out_127 = h_128 @ Wout^T + b_out  (h_128 is in hbf[0])
  {
    const char* hbR = reinterpret_cast<const char*>(hbf[0]);
    f32x4 aco = {0.f, 0.f, 0.f, 0.f};
#pragma unroll
    for (int kk = 0; kk < 8; kk++){
      int cb = (kk*64 + lg*16) ^ ((l15 & 7) << 4);
      bf16x8 a  = *reinterpret_cast<const bf16x8*>(hbR + l15*512 + cb);
      bf16x8 wo0 = *reinterpret_cast<const bf16x8*>(WoB + ((w*8 + kk)*64 + l)*8);
      aco = __builtin_amdgcn_mfma_f32_16x16x32_bf16(a, wo0, aco, 0, 0, 0);
    }
#pragma unroll
    for (int i = 0; i < 4; i++){
      int m = lg*4 + i;
      out[((r0 + m)*KSTEPS + 127)*OUTD + w*16 + l15] = aco[i] + bo;
    }
  }
}

extern "C" void kernel_launch(void* const* d_in, const int* in_sizes, int n_in,
                              void* d_out, int out_size, void* d_ws, size_t ws_size,
                              hipStream_t stream)
{
  const float* c     = (const float*)d_in[0];
  const float* W_ih  = (const float*)d_in[1];
  const float* W_hh  = (const float*)d_in[2];
  const float* b_ih  = (const float*)d_in[3];
  const float* b_hh  = (const float*)d_in[4];
  const float* W_out = (const float*)d_in[5];
  const float* b_out = (const float*)d_in[6];

  ushort_t* ws  = (ushort_t*)d_ws;
  ushort_t* WcB = ws;              // 262144 bf16
  ushort_t* W0B = ws + 262144;     // 262144 bf16
  ushort_t* WoB = ws + 524288;     //  32768 bf16

  hipLaunchKernelGGL(prep_weights, dim3(272), dim3(256), 0, stream,
                     W_ih, W_hh, W_out, ws);
  hipLaunchKernelGGL(gru_main, dim3(128), dim3(512), 0, stream,
                     c, b_ih, b_hh, b_out, WcB, W0B, WoB, (float*)d_out);
}